// Round 16
// baseline (2299.485 us; speedup 1.0000x reference)
//
#include <hip/hip_runtime.h>
#include <math.h>

#define B_    32
#define T_    256
#define HID_  512
#define G4_   2048   // 4*HID
#define VOC_  10000
#define NPAD_ 10112  // 79*128, padded vocab for the bf16 GEMM

typedef float f32x4 __attribute__((ext_vector_type(4)));
typedef short bf16x8 __attribute__((ext_vector_type(8)));
typedef unsigned short u16;
typedef u16 u16x8 __attribute__((ext_vector_type(8)));

#define AADD(p)  __hip_atomic_fetch_add((p), 1u, __ATOMIC_RELAXED, __HIP_MEMORY_SCOPE_AGENT)
#define ALOAD(p) __hip_atomic_load((p), __ATOMIC_RELAXED, __HIP_MEMORY_SCOPE_AGENT)

// Drain ALL of this wave's outstanding VMEM ops (incl. inline-asm stores the
// compiler's waitcnt pass cannot see) before the arrival barrier. r13-proven:
// closes the producer->consumer visibility race at full speed.
#define DRAIN_STORES() do { \
    asm volatile("s_waitcnt vmcnt(0)" ::: "memory"); \
    __builtin_amdgcn_sched_barrier(0); \
} while (0)

// ---------------- coherent (cross-XCD via IF$) helpers: sc0 sc1 ------------
__device__ __forceinline__ void load4_coherent(const float* p0, const float* p1,
                                               const float* p2, const float* p3,
                                               f32x4& a, f32x4& b, f32x4& c, f32x4& d)
{
    asm volatile(
        "global_load_dwordx4 %0, %4, off sc0 sc1\n\t"
        "global_load_dwordx4 %1, %5, off sc0 sc1\n\t"
        "global_load_dwordx4 %2, %6, off sc0 sc1\n\t"
        "global_load_dwordx4 %3, %7, off sc0 sc1\n\t"
        "s_waitcnt vmcnt(0)"
        : "=&v"(a), "=&v"(b), "=&v"(c), "=&v"(d)
        : "v"(p0), "v"(p1), "v"(p2), "v"(p3)
        : "memory");
}
__device__ __forceinline__ void store_coherent(float* p, float x)
{
    asm volatile("global_store_dword %0, %1, off sc0 sc1" :: "v"(p), "v"(x) : "memory");
}

__device__ __forceinline__ float fsigm(float x)
{
    float e = exp2f(x * -1.4426950408889634f);
    return __builtin_amdgcn_rcpf(1.f + e);
}
__device__ __forceinline__ float ftanh(float x)
{
    float e = exp2f(x * 2.8853900817779268f);
    return 1.f - 2.f * __builtin_amdgcn_rcpf(e + 1.f);
}

// fp32 -> bf16_hi + bf16_lo (RNE both; a ~= hi + lo with ~16 mantissa bits)
__device__ __forceinline__ void bsplit(float x, u16& hi, u16& lo)
{
    union { float f; unsigned u; } a; a.f = x;
    unsigned r = a.u + 0x7FFFu + ((a.u >> 16) & 1u);
    hi = (u16)(r >> 16);
    union { unsigned u; float f; } hf; hf.u = ((unsigned)hi) << 16;
    union { float f; unsigned u; } b; b.f = x - hf.f;
    unsigned r2 = b.u + 0x7FFFu + ((b.u >> 16) & 1u);
    lo = (u16)(r2 >> 16);
}

// ---------------------------------------------------------------------------
// Transpose + split: W [512][N] fp32 -> WT_hi/lo [Npad][512] bf16 (n-major)
// ---------------------------------------------------------------------------
__global__ __launch_bounds__(256)
void wsplit_k(const float* __restrict__ W, u16* __restrict__ Thi,
              u16* __restrict__ Tlo, int N)
{
    __shared__ float tile[64][68];
    const int tid = threadIdx.x;
    const int n0 = blockIdx.x * 64;
    const int k0 = blockIdx.y * 64;

    #pragma unroll
    for (int it = 0; it < 4; ++it) {
        int idx = it * 256 + tid;
        int kr = idx >> 4;
        int nc = (idx & 15) * 4;
        int n  = n0 + nc;
        float4 v = {0.f, 0.f, 0.f, 0.f};
        const float* wp = W + (size_t)(k0 + kr) * N + n;
        if (n + 3 < N) v = *(const float4*)wp;
        else {
            if (n + 0 < N) v.x = wp[0];
            if (n + 1 < N) v.y = wp[1];
            if (n + 2 < N) v.z = wp[2];
            if (n + 3 < N) v.w = wp[3];
        }
        tile[kr][nc + 0] = v.x; tile[kr][nc + 1] = v.y;
        tile[kr][nc + 2] = v.z; tile[kr][nc + 3] = v.w;
    }
    __syncthreads();

    #pragma unroll
    for (int it = 0; it < 2; ++it) {
        int idx = it * 256 + tid;
        int nr = idx >> 3;
        int kb = (idx & 7) * 8;
        u16x8 hv, lv;
        #pragma unroll
        for (int e = 0; e < 8; ++e) {
            u16 h, l;
            bsplit(tile[kb + e][nr], h, l);
            hv[e] = h; lv[e] = l;
        }
        size_t o = (size_t)(n0 + nr) * 512 + k0 + kb;
        *(u16x8*)(Thi + o) = hv;
        *(u16x8*)(Tlo + o) = lv;
    }
}

// ---------------------------------------------------------------------------
// Gather + split: A[r][:] = emb[tokens], r = t*32+b -> Ahi/Alo [8192][512]
// ---------------------------------------------------------------------------
__global__ __launch_bounds__(256)
void gather_split_k(const int* __restrict__ tokens, const float* __restrict__ emb,
                    u16* __restrict__ Ahi, u16* __restrict__ Alo)
{
    const int r    = blockIdx.x * 4 + (threadIdx.x >> 6);
    const int lane = threadIdx.x & 63;
    const int tok  = tokens[(r & 31) * T_ + (r >> 5)];
    const float* src = emb + (size_t)tok * 512 + lane * 8;
    float4 v0 = *(const float4*)(src);
    float4 v1 = *(const float4*)(src + 4);
    const float vv[8] = {v0.x, v0.y, v0.z, v0.w, v1.x, v1.y, v1.z, v1.w};
    u16x8 hv, lv;
    #pragma unroll
    for (int e = 0; e < 8; ++e) { u16 h, l; bsplit(vv[e], h, l); hv[e] = h; lv[e] = l; }
    size_t o = (size_t)r * 512 + lane * 8;
    *(u16x8*)(Ahi + o) = hv;
    *(u16x8*)(Alo + o) = lv;
}

// ---------------------------------------------------------------------------
// Split-bf16 MFMA GEMM (unchanged; proven)
// ---------------------------------------------------------------------------
template<int MODE>
__global__ __launch_bounds__(256)
void gemm_bf16_k(const u16* __restrict__ Ahi, const u16* __restrict__ Alo,
                 const u16* __restrict__ Bhi, const u16* __restrict__ Blo,
                 const float* __restrict__ bias, float* __restrict__ C, int N)
{
    __shared__ u16 As[2][128 * 64];
    __shared__ u16 Bs[2][128 * 64];

    const int tid  = threadIdx.x;
    const int lane = tid & 63;
    const int wid  = tid >> 6;
    const int wm   = wid >> 1;
    const int wn   = wid & 1;
    const int m0   = blockIdx.y * 128;
    const int n0   = blockIdx.x * 128;

    f32x4 acc[4][4];
    #pragma unroll
    for (int i = 0; i < 4; ++i)
        #pragma unroll
        for (int j = 0; j < 4; ++j) acc[i][j] = (f32x4){0.f, 0.f, 0.f, 0.f};

    auto stage = [&](int s, int buf) {
        const int ksel = s >> 3;
        const int koff = (s & 7) * 64;
        const u16* Asrc = (ksel == 2) ? Alo : Ahi;
        const u16* Bsrc = (ksel == 1) ? Blo : Bhi;
        #pragma unroll
        for (int q = 0; q < 4; ++q) {
            const int u   = q * 256 + tid;
            const int row = u >> 3;
            const int kch = (u & 7) ^ (row & 7);
            const u16* ga = Asrc + (size_t)(m0 + row) * 512 + koff + kch * 8;
            const u16* gb = Bsrc + (size_t)(n0 + row) * 512 + koff + kch * 8;
            u16* la = &As[buf][(q * 256 + wid * 64) * 8];
            u16* lb = &Bs[buf][(q * 256 + wid * 64) * 8];
            __builtin_amdgcn_global_load_lds(
                (const __attribute__((address_space(1))) void*)ga,
                (__attribute__((address_space(3))) void*)la, 16, 0, 0);
            __builtin_amdgcn_global_load_lds(
                (const __attribute__((address_space(1))) void*)gb,
                (__attribute__((address_space(3))) void*)lb, 16, 0, 0);
        }
    };

    stage(0, 0);
    for (int s = 0; s < 24; ++s) {
        const int buf = s & 1;
        __syncthreads();
        if (s + 1 < 24) stage(s + 1, buf ^ 1);

        #pragma unroll
        for (int q = 0; q < 2; ++q) {
            bf16x8 af[4], bfr[4];
            #pragma unroll
            for (int mt = 0; mt < 4; ++mt) {
                const int r    = wm * 64 + mt * 16 + (lane & 15);
                const int slot = (q * 4 + (lane >> 4)) ^ (r & 7);
                af[mt] = *(const bf16x8*)&As[buf][r * 64 + slot * 8];
            }
            #pragma unroll
            for (int nt = 0; nt < 4; ++nt) {
                const int rn   = wn * 64 + nt * 16 + (lane & 15);
                const int slot = (q * 4 + (lane >> 4)) ^ (rn & 7);
                bfr[nt] = *(const bf16x8*)&Bs[buf][rn * 64 + slot * 8];
            }
            #pragma unroll
            for (int mt = 0; mt < 4; ++mt)
                #pragma unroll
                for (int nt = 0; nt < 4; ++nt)
                    acc[mt][nt] = __builtin_amdgcn_mfma_f32_16x16x32_bf16(
                        af[mt], bfr[nt], acc[mt][nt], 0, 0, 0);
        }
    }

    #pragma unroll
    for (int mt = 0; mt < 4; ++mt) {
        #pragma unroll
        for (int nt = 0; nt < 4; ++nt) {
            const int c = n0 + wn * 64 + nt * 16 + (lane & 15);
            #pragma unroll
            for (int j = 0; j < 4; ++j) {
                const int r = m0 + wm * 64 + mt * 16 + (lane >> 4) * 4 + j;
                float val = acc[mt][nt][j];
                if constexpr (MODE == 0) {
                    val += bias[c];
                    const int t = r >> 5, bgrp = (r >> 3) & 3, bb = r & 7;
                    const int g = c >> 9, jblk = (c & 511) >> 3, jjs = c & 7;
                    C[(((size_t)t * 4 + bgrp) * 64 + jblk) * 256 + bb * 32 + g * 8 + jjs] = val;
                } else {
                    if (c < VOC_) {
                        val += bias[c];
                        const size_t orow = (size_t)(r & 31) * T_ + (r >> 5);
                        C[orow * VOC_ + c] = val;
                    }
                }
            }
        }
    }
}

// ---------------------------------------------------------------------------
// FUSED 2-layer LSTM recurrence, persistent: 512 blocks x 256 thr (2/CU).
// r14-verbatim EXCEPT the barrier loses its root hop:
//   arrival  = tid0 AADD(own shard)            (1 atomic, 16 blocks/shard)
//   wait     = 4 lanes poll the dep group's 4 shard counters + __all
// This removes one agent-atomic round-trip (~0.7-1us) and the last-arriver
// serialization from EVERY step's critical path. Correctness: the r7/r12
// failures of this polling shape are attributed (r13 A/B) to the missing
// DRAIN_STORES, which is kept here -- each wave drains its inline-asm
// coherent stores (hardware vmcnt counts them) BEFORE the barrier, so the
// shard add happens-after all of the block's h stores are at IF$.
// Blocks 0..255 = LAYER 0; blocks 256..511 = LAYER 1 (concat K=1024).
// Layer 0 never waits on layer 1 => deadlock-free at ANY residency.
// ---------------------------------------------------------------------------
__global__ __launch_bounds__(256, 1)
void fused_rec_k(const float* __restrict__ G, const float* __restrict__ U0,
                 const float* __restrict__ W1, const float* __restrict__ U1,
                 const float* __restrict__ b1,
                 float* __restrict__ H0x,      // [T+1][32][512], slot0 zeroed
                 u16* __restrict__ Ahi, u16* __restrict__ Alo,
                 float* __restrict__ h1buf,    // [2][32][512], slot0 zeroed
                 unsigned* __restrict__ bar)
{
    __shared__ float lds[8 * 1152];      // L0 uses [8][640]; L1 uses [8][32][36]

    const int tid  = threadIdx.x;
    const int role = blockIdx.x >> 8;    // 0 = layer0, 1 = layer1
    const int blk  = blockIdx.x & 255;
    const int bg   = blk >> 6;           // 0..3  batch group
    const int cgr  = blk & 63;           // 0..63 column group
    const int j0   = cgr * 8;
    const int b0   = bg * 8;

    const int jj  = tid >> 5;            // 0..7
    const int kc  = tid & 31;            // 0..31 K-chunk
    const int g_  = kc >> 3;             // gate after reduce-scatter
    const int bb_ = kc & 7;              // batch after reduce-scatter
    const int shard = cgr & 3;

    // shard layout: role0 group bg -> bar[bg*64 + s*16], s=0..3 (16 blocks each)
    //               role1 group bg -> bar[512 + bg*64 + s*16]
    unsigned* sh0base = bar + bg * 64;
    unsigned* sh1base = bar + 512 + bg * 64;
    unsigned* myshard = (role == 0 ? sh0base : sh1base) + shard * 16;

    // lane-parallel shard wait: lanes 0-3 poll p1-set, lanes 8-11 poll p2-set
    auto wait_shards = [&](const unsigned* base1, unsigned tgt1,
                           const unsigned* base2, unsigned tgt2) {
        if (tid < 64) {
            unsigned guard = 0;
            for (;;) {
                bool ok = true;
                if (tid < 4)                       ok = (ALOAD(base1 + tid * 16) >= tgt1);
                else if (tid >= 8 && tid < 12 && base2)
                                                   ok = (ALOAD(base2 + (tid - 8) * 16) >= tgt2);
                if (__all((int)ok)) break;
                __builtin_amdgcn_s_sleep(1);
                if (++guard > 100000000u) break;   // hang-safety
            }
        }
    };

    if (role == 0) {
        // ---------------- LAYER 0 ----------------
        float u[4][16];
        #pragma unroll
        for (int g = 0; g < 4; ++g)
            #pragma unroll
            for (int kk = 0; kk < 16; ++kk)
                u[g][kk] = U0[(size_t)(kc * 16 + kk) * G4_ + (g << 9) + j0 + jj];

        const int gofs = bb_ * 32 + g_ * 8 + jj;
        float zpre = G[((size_t)bg * 64 + cgr) * 256 + gofs];
        float c_reg = 0.f;

        for (int t = 0; t < T_; ++t) {
            if (t > 0) wait_shards(sh0base, 16u * (unsigned)t, nullptr, 0u);
            __syncthreads();                       // SYNC_A: h0(t) ready, lds free

            // stage h0(t)=H0x[t] [8][512] -> lds (stride-20 padded)
            {
                const float* p[4]; float* dst[4];
                const float* hcur = H0x + (size_t)t * (B_ * HID_);
                #pragma unroll
                for (int q = 0; q < 4; ++q) {
                    int idx = q * 256 + tid;
                    int bL  = idx >> 7;
                    int k4  = idx & 127;
                    p[q]   = hcur + (b0 + bL) * HID_ + k4 * 4;
                    dst[q] = &lds[bL * 640 + (k4 >> 2) * 20 + (k4 & 3) * 4];
                }
                f32x4 v0, v1, v2, v3;
                load4_coherent(p[0], p[1], p[2], p[3], v0, v1, v2, v3);
                *(f32x4*)dst[0] = v0; *(f32x4*)dst[1] = v1;
                *(f32x4*)dst[2] = v2; *(f32x4*)dst[3] = v3;
            }
            __syncthreads();                       // SYNC_B

            float zpre_next = 0.f;
            if (t + 1 < T_)
                zpre_next = G[((size_t)((t + 1) * 4 + bg) * 64 + cgr) * 256 + gofs];

            float v[32];
            #pragma unroll
            for (int s = 0; s < 32; ++s) v[s] = 0.f;
            #pragma unroll
            for (int bb = 0; bb < 8; ++bb) {
                const float* hp = &lds[bb * 640 + kc * 20];
                f32x4 h0v = *(const f32x4*)(hp + 0);
                f32x4 h1v = *(const f32x4*)(hp + 4);
                f32x4 h2v = *(const f32x4*)(hp + 8);
                f32x4 h3v = *(const f32x4*)(hp + 12);
                const float hh[16] = {h0v.x, h0v.y, h0v.z, h0v.w, h1v.x, h1v.y, h1v.z, h1v.w,
                                      h2v.x, h2v.y, h2v.z, h2v.w, h3v.x, h3v.y, h3v.z, h3v.w};
                #pragma unroll
                for (int g = 0; g < 4; ++g)
                    #pragma unroll
                    for (int kk = 0; kk < 16; ++kk)
                        v[g * 8 + bb] += u[g][kk] * hh[kk];
            }

            // reduce-scatter over 32 kc lanes
            float a16[16];
            #pragma unroll
            for (int i = 0; i < 16; ++i) {
                float keep = (kc & 16) ? v[i + 16] : v[i];
                float give = (kc & 16) ? v[i]      : v[i + 16];
                a16[i] = keep + __shfl_xor(give, 16, 32);
            }
            float a8[8];
            #pragma unroll
            for (int i = 0; i < 8; ++i) {
                float keep = (kc & 8) ? a16[i + 8] : a16[i];
                float give = (kc & 8) ? a16[i]     : a16[i + 8];
                a8[i] = keep + __shfl_xor(give, 8, 32);
            }
            float a4[4];
            #pragma unroll
            for (int i = 0; i < 4; ++i) {
                float keep = (kc & 4) ? a8[i + 4] : a8[i];
                float give = (kc & 4) ? a8[i]     : a8[i + 4];
                a4[i] = keep + __shfl_xor(give, 4, 32);
            }
            float a2[2];
            #pragma unroll
            for (int i = 0; i < 2; ++i) {
                float keep = (kc & 2) ? a4[i + 2] : a4[i];
                float give = (kc & 2) ? a4[i]     : a4[i + 2];
                a2[i] = keep + __shfl_xor(give, 2, 32);
            }
            float keep1 = (kc & 1) ? a2[1] : a2[0];
            float give1 = (kc & 1) ? a2[0] : a2[1];
            float z = keep1 + __shfl_xor(give1, 1, 32) + zpre;
            zpre = zpre_next;

            float z8  = __shfl_xor(z, 8, 32);
            float z16 = __shfl_xor(z, 16, 32);
            float z24 = __shfl_xor(z, 24, 32);
            float i_ = fsigm(z);
            float f_ = fsigm(z8);
            float gg = ftanh(z16);
            float o_ = fsigm(z24);
            c_reg = f_ * c_reg + i_ * gg;
            float h_ = o_ * ftanh(c_reg);

            if (g_ == 0)
                store_coherent(&H0x[(size_t)(t + 1) * (B_ * HID_)
                                    + (b0 + bb_) * HID_ + j0 + jj], h_);

            DRAIN_STORES();                        // asm stores at IF$ before arrival
            __syncthreads();                       // SYNC_C
            if (tid == 0) AADD(myshard);           // fire-and-forget arrival
        }
    } else {
        // ---------------- LAYER 1 ----------------
        // concatenated K=1024: kc<16 -> W1 rows (x part), kc>=16 -> U1 (h part)
        float u[4][32];
        #pragma unroll
        for (int g = 0; g < 4; ++g)
            #pragma unroll
            for (int kk = 0; kk < 32; ++kk) {
                const int K = kc * 32 + kk;
                u[g][kk] = (K < 512)
                    ? W1[(size_t)K * G4_ + (g << 9) + j0 + jj]
                    : U1[(size_t)(K - 512) * G4_ + (g << 9) + j0 + jj];
            }
        const float zb = b1[(g_ << 9) + j0 + jj];
        float c_reg = 0.f;

        for (int t = 0; t < T_; ++t) {
            wait_shards(sh0base, 16u * (unsigned)(t + 1),              // h0(t) ready
                        (t > 0) ? sh1base : nullptr, 16u * (unsigned)t); // h1(t) ready
            __syncthreads();                       // SYNC_A

            // stage [x=h0(t) | h1(t)] [8][1024] -> lds[b][kc][36]
            {
                const float* xbase = H0x  + (size_t)(t + 1) * (B_ * HID_);
                const float* hbase = h1buf + (size_t)(t & 1) * (B_ * HID_);
                const float* p[8]; float* dst[8];
                const int k = tid * 4;             // 0..1020
                #pragma unroll
                for (int q = 0; q < 8; ++q) {
                    p[q] = (k < 512) ? (xbase + (b0 + q) * HID_ + k)
                                     : (hbase + (b0 + q) * HID_ + (k - 512));
                    dst[q] = &lds[q * 1152 + (tid >> 3) * 36 + (tid & 7) * 4];
                }
                f32x4 v0, v1, v2, v3, v4, v5, v6, v7;
                load4_coherent(p[0], p[1], p[2], p[3], v0, v1, v2, v3);
                load4_coherent(p[4], p[5], p[6], p[7], v4, v5, v6, v7);
                *(f32x4*)dst[0] = v0; *(f32x4*)dst[1] = v1;
                *(f32x4*)dst[2] = v2; *(f32x4*)dst[3] = v3;
                *(f32x4*)dst[4] = v4; *(f32x4*)dst[5] = v5;
                *(f32x4*)dst[6] = v6; *(f32x4*)dst[7] = v7;
            }
            __syncthreads();                       // SYNC_B

            float v[32];
            #pragma unroll
            for (int s = 0; s < 32; ++s) v[s] = 0.f;
            #pragma unroll
            for (int bb = 0; bb < 8; ++bb) {
                const float* hp = &lds[bb * 1152 + kc * 36];
                #pragma unroll
                for (int half = 0; half < 2; ++half) {
                    f32x4 h0v = *(const f32x4*)(hp + half * 16 + 0);
                    f32x4 h1v = *(const f32x4*)(hp + half * 16 + 4);
                    f32x4 h2v = *(const f32x4*)(hp + half * 16 + 8);
                    f32x4 h3v = *(const f32x4*)(hp + half * 16 + 12);
                    const float hh[16] = {h0v.x, h0v.y, h0v.z, h0v.w, h1v.x, h1v.y, h1v.z, h1v.w,
                                          h2v.x, h2v.y, h2v.z, h2v.w, h3v.x, h3v.y, h3v.z, h3v.w};
                    #pragma unroll
                    for (int g = 0; g < 4; ++g)
                        #pragma unroll
                        for (int kk = 0; kk < 16; ++kk)
                            v[g * 8 + bb] += u[g][half * 16 + kk] * hh[kk];
                }
            }

            float a16[16];
            #pragma unroll
            for (int i = 0; i < 16; ++i) {
                float keep = (kc & 16) ? v[i + 16] : v[i];
                float give = (kc & 16) ? v[i]      : v[i + 16];
                a16[i] = keep + __shfl_xor(give, 16, 32);
            }
            float a8[8];
            #pragma unroll
            for (int i = 0; i < 8; ++i) {
                float keep = (kc & 8) ? a16[i + 8] : a16[i];
                float give = (kc & 8) ? a16[i]     : a16[i + 8];
                a8[i] = keep + __shfl_xor(give, 8, 32);
            }
            float a4[4];
            #pragma unroll
            for (int i = 0; i < 4; ++i) {
                float keep = (kc & 4) ? a8[i + 4] : a8[i];
                float give = (kc & 4) ? a8[i]     : a8[i + 4];
                a4[i] = keep + __shfl_xor(give, 4, 32);
            }
            float a2[2];
            #pragma unroll
            for (int i = 0; i < 2; ++i) {
                float keep = (kc & 2) ? a4[i + 2] : a4[i];
                float give = (kc & 2) ? a4[i]     : a4[i + 2];
                a2[i] = keep + __shfl_xor(give, 2, 32);
            }
            float keep1 = (kc & 1) ? a2[1] : a2[0];
            float give1 = (kc & 1) ? a2[0] : a2[1];
            float z = keep1 + __shfl_xor(give1, 1, 32) + zb;

            float z8  = __shfl_xor(z, 8, 32);
            float z16 = __shfl_xor(z, 16, 32);
            float z24 = __shfl_xor(z, 24, 32);
            float i_ = fsigm(z);
            float f_ = fsigm(z8);
            float gg = ftanh(z16);
            float o_ = fsigm(z24);
            c_reg = f_ * c_reg + i_ * gg;
            float h_ = o_ * ftanh(c_reg);

            if (g_ == 0) {
                const int brow = b0 + bb_;
                store_coherent(&h1buf[(size_t)((t + 1) & 1) * (B_ * HID_)
                                      + brow * HID_ + j0 + jj], h_);
                u16 hi, lo; bsplit(h_, hi, lo);
                const size_t o = ((size_t)t * B_ + brow) * HID_ + j0 + jj;
                Ahi[o] = hi;
                Alo[o] = lo;
            }

            DRAIN_STORES();                        // asm stores at IF$ before arrival
            __syncthreads();                       // SYNC_C
            if (tid == 0) AADD(myshard);           // fire-and-forget arrival
        }
    }
}

// ---------------------------------------------------------------------------
extern "C" void kernel_launch(void* const* d_in, const int* in_sizes, int n_in,
                              void* d_out, int out_size, void* d_ws, size_t ws_size,
                              hipStream_t stream)
{
    const int*   tokens = (const int*)  d_in[0];
    const float* emb    = (const float*)d_in[1];
    const float* W0     = (const float*)d_in[2];
    const float* U0     = (const float*)d_in[3];
    const float* b0     = (const float*)d_in[4];
    const float* W1     = (const float*)d_in[5];
    const float* U1     = (const float*)d_in[6];
    const float* b1     = (const float*)d_in[7];
    const float* Wout   = (const float*)d_in[8];
    const float* bout   = (const float*)d_in[9];
    float* out = (float*)d_out;

    // d_out scratch: G (8192x2048 fp32 swizzled) then H0x ([T+1][32][512]) --
    // both dead before the final GEMM overwrites all of d_out.
    float* G   = out;
    float* H0x = out + (size_t)8192 * 2048;

    u16* ws16 = (u16*)d_ws;
    size_t o = 0;
    u16* Ahi   = ws16 + o; o += (size_t)8192 * 512;
    u16* Alo   = ws16 + o; o += (size_t)8192 * 512;
    u16* W0Thi = ws16 + o; o += (size_t)G4_ * 512;
    u16* W0Tlo = ws16 + o; o += (size_t)G4_ * 512;
    u16* WoThi = ws16 + o; o += (size_t)NPAD_ * 512;
    u16* WoTlo = ws16 + o; o += (size_t)NPAD_ * 512;
    float*    h1buf = (float*)(ws16 + o);
    unsigned* bar   = (unsigned*)(h1buf + 2 * B_ * HID_);

    dim3 blk(256);

    // prep: weight transpose+split (W0, Wout) and embedding gather+split
    wsplit_k<<<dim3(G4_ / 64, 8), blk, 0, stream>>>(W0, W0Thi, W0Tlo, G4_);
    wsplit_k<<<dim3(NPAD_ / 64, 8), blk, 0, stream>>>(Wout, WoThi, WoTlo, VOC_);
    gather_split_k<<<dim3(2048), blk, 0, stream>>>(tokens, emb, Ahi, Alo);

    // G = X0 @ W0 + b0   (split-bf16 MFMA, recurrence-swizzled store)
    gemm_bf16_k<0><<<dim3(G4_ / 128, 64), blk, 0, stream>>>(
        Ahi, Alo, W0Thi, W0Tlo, b0, G, G4_);

    // fused 2-layer recurrence -> Ahi/Alo (h1 bf16)
    hipMemsetAsync(H0x, 0, B_ * HID_ * sizeof(float), stream);    // h0(0) = 0
    hipMemsetAsync(h1buf, 0, B_ * HID_ * sizeof(float), stream);  // h1(0) = 0
    hipMemsetAsync(bar, 0, 1024 * sizeof(unsigned), stream);      // barriers
    fused_rec_k<<<dim3(512), blk, 0, stream>>>(
        G, U0, W1, U1, b1, H0x, Ahi, Alo, h1buf, bar);

    // out[b*T+t, :] = H1 @ W_out + b_out
    gemm_bf16_k<1><<<dim3(NPAD_ / 128, 64), blk, 0, stream>>>(
        Ahi, Alo, WoThi, WoTlo, bout, out, NPAD_);
}

// Round 17
// 2220.132 us; speedup vs baseline: 1.0357x; 1.0357x over previous
//
#include <hip/hip_runtime.h>
#include <math.h>

#define B_    32
#define T_    256
#define HID_  512
#define G4_   2048   // 4*HID
#define VOC_  10000
#define NPAD_ 10112  // 79*128, padded vocab for the bf16 GEMM

typedef float f32x4 __attribute__((ext_vector_type(4)));
typedef short bf16x8 __attribute__((ext_vector_type(8)));
typedef unsigned short u16;
typedef u16 u16x8 __attribute__((ext_vector_type(8)));

#define AADD(p)  __hip_atomic_fetch_add((p), 1u, __ATOMIC_RELAXED, __HIP_MEMORY_SCOPE_AGENT)
#define ALOAD(p) __hip_atomic_load((p), __ATOMIC_RELAXED, __HIP_MEMORY_SCOPE_AGENT)

// Drain ALL of this wave's outstanding VMEM ops (incl. inline-asm stores the
// compiler's waitcnt pass cannot see) before the arrival barrier. r13-proven:
// closes the producer->consumer visibility race at full speed.
#define DRAIN_STORES() do { \
    asm volatile("s_waitcnt vmcnt(0)" ::: "memory"); \
    __builtin_amdgcn_sched_barrier(0); \
} while (0)

// ---------------- coherent (cross-XCD via IF$) helpers: sc0 sc1 ------------
__device__ __forceinline__ void load4_coherent(const float* p0, const float* p1,
                                               const float* p2, const float* p3,
                                               f32x4& a, f32x4& b, f32x4& c, f32x4& d)
{
    asm volatile(
        "global_load_dwordx4 %0, %4, off sc0 sc1\n\t"
        "global_load_dwordx4 %1, %5, off sc0 sc1\n\t"
        "global_load_dwordx4 %2, %6, off sc0 sc1\n\t"
        "global_load_dwordx4 %3, %7, off sc0 sc1\n\t"
        "s_waitcnt vmcnt(0)"
        : "=&v"(a), "=&v"(b), "=&v"(c), "=&v"(d)
        : "v"(p0), "v"(p1), "v"(p2), "v"(p3)
        : "memory");
}
__device__ __forceinline__ void store_coherent(float* p, float x)
{
    asm volatile("global_store_dword %0, %1, off sc0 sc1" :: "v"(p), "v"(x) : "memory");
}

__device__ __forceinline__ float fsigm(float x)
{
    float e = exp2f(x * -1.4426950408889634f);
    return __builtin_amdgcn_rcpf(1.f + e);
}
__device__ __forceinline__ float ftanh(float x)
{
    float e = exp2f(x * 2.8853900817779268f);
    return 1.f - 2.f * __builtin_amdgcn_rcpf(e + 1.f);
}

// fp32 -> bf16_hi + bf16_lo (RNE both; a ~= hi + lo with ~16 mantissa bits)
__device__ __forceinline__ void bsplit(float x, u16& hi, u16& lo)
{
    union { float f; unsigned u; } a; a.f = x;
    unsigned r = a.u + 0x7FFFu + ((a.u >> 16) & 1u);
    hi = (u16)(r >> 16);
    union { unsigned u; float f; } hf; hf.u = ((unsigned)hi) << 16;
    union { float f; unsigned u; } b; b.f = x - hf.f;
    unsigned r2 = b.u + 0x7FFFu + ((b.u >> 16) & 1u);
    lo = (u16)(r2 >> 16);
}

// spin until *p >= tgt (monotonic counter), with hang-safety bail
__device__ __forceinline__ void wait_ge(unsigned* p, unsigned tgt)
{
    unsigned g = 0;
    while (ALOAD(p) < tgt) {
        __builtin_amdgcn_s_sleep(2);
        if (++g > 100000000u) break;
    }
}

// ---------------------------------------------------------------------------
// Transpose + split: W [512][N] fp32 -> WT_hi/lo [Npad][512] bf16 (n-major)
// ---------------------------------------------------------------------------
__global__ __launch_bounds__(256)
void wsplit_k(const float* __restrict__ W, u16* __restrict__ Thi,
              u16* __restrict__ Tlo, int N)
{
    __shared__ float tile[64][68];
    const int tid = threadIdx.x;
    const int n0 = blockIdx.x * 64;
    const int k0 = blockIdx.y * 64;

    #pragma unroll
    for (int it = 0; it < 4; ++it) {
        int idx = it * 256 + tid;
        int kr = idx >> 4;
        int nc = (idx & 15) * 4;
        int n  = n0 + nc;
        float4 v = {0.f, 0.f, 0.f, 0.f};
        const float* wp = W + (size_t)(k0 + kr) * N + n;
        if (n + 3 < N) v = *(const float4*)wp;
        else {
            if (n + 0 < N) v.x = wp[0];
            if (n + 1 < N) v.y = wp[1];
            if (n + 2 < N) v.z = wp[2];
            if (n + 3 < N) v.w = wp[3];
        }
        tile[kr][nc + 0] = v.x; tile[kr][nc + 1] = v.y;
        tile[kr][nc + 2] = v.z; tile[kr][nc + 3] = v.w;
    }
    __syncthreads();

    #pragma unroll
    for (int it = 0; it < 2; ++it) {
        int idx = it * 256 + tid;
        int nr = idx >> 3;
        int kb = (idx & 7) * 8;
        u16x8 hv, lv;
        #pragma unroll
        for (int e = 0; e < 8; ++e) {
            u16 h, l;
            bsplit(tile[kb + e][nr], h, l);
            hv[e] = h; lv[e] = l;
        }
        size_t o = (size_t)(n0 + nr) * 512 + k0 + kb;
        *(u16x8*)(Thi + o) = hv;
        *(u16x8*)(Tlo + o) = lv;
    }
}

// ---------------------------------------------------------------------------
// Gather + split: A[r][:] = emb[tokens], r = t*32+b -> Ahi/Alo [8192][512]
// ---------------------------------------------------------------------------
__global__ __launch_bounds__(256)
void gather_split_k(const int* __restrict__ tokens, const float* __restrict__ emb,
                    u16* __restrict__ Ahi, u16* __restrict__ Alo)
{
    const int r    = blockIdx.x * 4 + (threadIdx.x >> 6);
    const int lane = threadIdx.x & 63;
    const int tok  = tokens[(r & 31) * T_ + (r >> 5)];
    const float* src = emb + (size_t)tok * 512 + lane * 8;
    float4 v0 = *(const float4*)(src);
    float4 v1 = *(const float4*)(src + 4);
    const float vv[8] = {v0.x, v0.y, v0.z, v0.w, v1.x, v1.y, v1.z, v1.w};
    u16x8 hv, lv;
    #pragma unroll
    for (int e = 0; e < 8; ++e) { u16 h, l; bsplit(vv[e], h, l); hv[e] = h; lv[e] = l; }
    size_t o = (size_t)r * 512 + lane * 8;
    *(u16x8*)(Ahi + o) = hv;
    *(u16x8*)(Alo + o) = lv;
}

// ---------------------------------------------------------------------------
// Split-bf16 MFMA GEMM (unchanged; proven)
// ---------------------------------------------------------------------------
template<int MODE>
__global__ __launch_bounds__(256)
void gemm_bf16_k(const u16* __restrict__ Ahi, const u16* __restrict__ Alo,
                 const u16* __restrict__ Bhi, const u16* __restrict__ Blo,
                 const float* __restrict__ bias, float* __restrict__ C, int N)
{
    __shared__ u16 As[2][128 * 64];
    __shared__ u16 Bs[2][128 * 64];

    const int tid  = threadIdx.x;
    const int lane = tid & 63;
    const int wid  = tid >> 6;
    const int wm   = wid >> 1;
    const int wn   = wid & 1;
    const int m0   = blockIdx.y * 128;
    const int n0   = blockIdx.x * 128;

    f32x4 acc[4][4];
    #pragma unroll
    for (int i = 0; i < 4; ++i)
        #pragma unroll
        for (int j = 0; j < 4; ++j) acc[i][j] = (f32x4){0.f, 0.f, 0.f, 0.f};

    auto stage = [&](int s, int buf) {
        const int ksel = s >> 3;
        const int koff = (s & 7) * 64;
        const u16* Asrc = (ksel == 2) ? Alo : Ahi;
        const u16* Bsrc = (ksel == 1) ? Blo : Bhi;
        #pragma unroll
        for (int q = 0; q < 4; ++q) {
            const int u   = q * 256 + tid;
            const int row = u >> 3;
            const int kch = (u & 7) ^ (row & 7);
            const u16* ga = Asrc + (size_t)(m0 + row) * 512 + koff + kch * 8;
            const u16* gb = Bsrc + (size_t)(n0 + row) * 512 + koff + kch * 8;
            u16* la = &As[buf][(q * 256 + wid * 64) * 8];
            u16* lb = &Bs[buf][(q * 256 + wid * 64) * 8];
            __builtin_amdgcn_global_load_lds(
                (const __attribute__((address_space(1))) void*)ga,
                (__attribute__((address_space(3))) void*)la, 16, 0, 0);
            __builtin_amdgcn_global_load_lds(
                (const __attribute__((address_space(1))) void*)gb,
                (__attribute__((address_space(3))) void*)lb, 16, 0, 0);
        }
    };

    stage(0, 0);
    for (int s = 0; s < 24; ++s) {
        const int buf = s & 1;
        __syncthreads();
        if (s + 1 < 24) stage(s + 1, buf ^ 1);

        #pragma unroll
        for (int q = 0; q < 2; ++q) {
            bf16x8 af[4], bfr[4];
            #pragma unroll
            for (int mt = 0; mt < 4; ++mt) {
                const int r    = wm * 64 + mt * 16 + (lane & 15);
                const int slot = (q * 4 + (lane >> 4)) ^ (r & 7);
                af[mt] = *(const bf16x8*)&As[buf][r * 64 + slot * 8];
            }
            #pragma unroll
            for (int nt = 0; nt < 4; ++nt) {
                const int rn   = wn * 64 + nt * 16 + (lane & 15);
                const int slot = (q * 4 + (lane >> 4)) ^ (rn & 7);
                bfr[nt] = *(const bf16x8*)&Bs[buf][rn * 64 + slot * 8];
            }
            #pragma unroll
            for (int mt = 0; mt < 4; ++mt)
                #pragma unroll
                for (int nt = 0; nt < 4; ++nt)
                    acc[mt][nt] = __builtin_amdgcn_mfma_f32_16x16x32_bf16(
                        af[mt], bfr[nt], acc[mt][nt], 0, 0, 0);
        }
    }

    #pragma unroll
    for (int mt = 0; mt < 4; ++mt) {
        #pragma unroll
        for (int nt = 0; nt < 4; ++nt) {
            const int c = n0 + wn * 64 + nt * 16 + (lane & 15);
            #pragma unroll
            for (int j = 0; j < 4; ++j) {
                const int r = m0 + wm * 64 + mt * 16 + (lane >> 4) * 4 + j;
                float val = acc[mt][nt][j];
                if constexpr (MODE == 0) {
                    val += bias[c];
                    const int t = r >> 5, bgrp = (r >> 3) & 3, bb = r & 7;
                    const int g = c >> 9, jblk = (c & 511) >> 3, jjs = c & 7;
                    C[(((size_t)t * 4 + bgrp) * 64 + jblk) * 256 + bb * 32 + g * 8 + jjs] = val;
                } else {
                    if (c < VOC_) {
                        val += bias[c];
                        const size_t orow = (size_t)(r & 31) * T_ + (r >> 5);
                        C[orow * VOC_ + c] = val;
                    }
                }
            }
        }
    }
}

// ---------------------------------------------------------------------------
// FUSED 2-layer LSTM recurrence, persistent: 512 blocks x 256 thr (2/CU).
// Session-final configuration (r14: passed, 2265us, zero outlier dispatches):
// r11 structure + DRAIN_STORES before each arrival. The inline-asm coherent
// h stores are invisible to the compiler's waitcnt pass, so without an
// explicit vmcnt(0) a wave could publish its arrival while stores were
// still in flight to IF$ (the r7/r12 race). Hardware vmcnt counts asm VMEM.
// Blocks 0..255 = LAYER 0; blocks 256..511 = LAYER 1 (concat K=1024).
// Layer 0 never waits on layer 1 => deadlock-free at ANY residency.
// ---------------------------------------------------------------------------
__global__ __launch_bounds__(256, 1)
void fused_rec_k(const float* __restrict__ G, const float* __restrict__ U0,
                 const float* __restrict__ W1, const float* __restrict__ U1,
                 const float* __restrict__ b1,
                 float* __restrict__ H0x,      // [T+1][32][512], slot0 zeroed
                 u16* __restrict__ Ahi, u16* __restrict__ Alo,
                 float* __restrict__ h1buf,    // [2][32][512], slot0 zeroed
                 unsigned* __restrict__ bar)
{
    __shared__ float lds[8 * 1152];      // L0 uses [8][640]; L1 uses [8][32][36]

    const int tid  = threadIdx.x;
    const int role = blockIdx.x >> 8;    // 0 = layer0, 1 = layer1
    const int blk  = blockIdx.x & 255;
    const int bg   = blk >> 6;           // 0..3  batch group
    const int cgr  = blk & 63;           // 0..63 column group
    const int j0   = cgr * 8;
    const int b0   = bg * 8;

    const int jj  = tid >> 5;            // 0..7
    const int kc  = tid & 31;            // 0..31 K-chunk
    const int g_  = kc >> 3;             // gate after reduce-scatter
    const int bb_ = kc & 7;              // batch after reduce-scatter
    const int shard = cgr & 3;

    // barrier pointers: shards 64B apart, roots separate
    unsigned* shard0 = bar + (bg * 4 + shard) * 16;
    unsigned* root0  = bar + 256 + bg * 16;
    unsigned* shard1 = bar + 512 + (bg * 4 + shard) * 16;
    unsigned* root1  = bar + 768 + bg * 16;

    if (role == 0) {
        // ---------------- LAYER 0 ----------------
        float u[4][16];
        #pragma unroll
        for (int g = 0; g < 4; ++g)
            #pragma unroll
            for (int kk = 0; kk < 16; ++kk)
                u[g][kk] = U0[(size_t)(kc * 16 + kk) * G4_ + (g << 9) + j0 + jj];

        const int gofs = bb_ * 32 + g_ * 8 + jj;
        float zpre = G[((size_t)bg * 64 + cgr) * 256 + gofs];
        float c_reg = 0.f;

        for (int t = 0; t < T_; ++t) {
            if (tid == 0 && t > 0) wait_ge(root0, 4u * (unsigned)t);
            __syncthreads();                       // SYNC_A: h0(t) ready, lds free

            // stage h0(t)=H0x[t] [8][512] -> lds (stride-20 padded)
            {
                const float* p[4]; float* dst[4];
                const float* hcur = H0x + (size_t)t * (B_ * HID_);
                #pragma unroll
                for (int q = 0; q < 4; ++q) {
                    int idx = q * 256 + tid;
                    int bL  = idx >> 7;
                    int k4  = idx & 127;
                    p[q]   = hcur + (b0 + bL) * HID_ + k4 * 4;
                    dst[q] = &lds[bL * 640 + (k4 >> 2) * 20 + (k4 & 3) * 4];
                }
                f32x4 v0, v1, v2, v3;
                load4_coherent(p[0], p[1], p[2], p[3], v0, v1, v2, v3);
                *(f32x4*)dst[0] = v0; *(f32x4*)dst[1] = v1;
                *(f32x4*)dst[2] = v2; *(f32x4*)dst[3] = v3;
            }
            __syncthreads();                       // SYNC_B

            float zpre_next = 0.f;
            if (t + 1 < T_)
                zpre_next = G[((size_t)((t + 1) * 4 + bg) * 64 + cgr) * 256 + gofs];

            float v[32];
            #pragma unroll
            for (int s = 0; s < 32; ++s) v[s] = 0.f;
            #pragma unroll
            for (int bb = 0; bb < 8; ++bb) {
                const float* hp = &lds[bb * 640 + kc * 20];
                f32x4 h0v = *(const f32x4*)(hp + 0);
                f32x4 h1v = *(const f32x4*)(hp + 4);
                f32x4 h2v = *(const f32x4*)(hp + 8);
                f32x4 h3v = *(const f32x4*)(hp + 12);
                const float hh[16] = {h0v.x, h0v.y, h0v.z, h0v.w, h1v.x, h1v.y, h1v.z, h1v.w,
                                      h2v.x, h2v.y, h2v.z, h2v.w, h3v.x, h3v.y, h3v.z, h3v.w};
                #pragma unroll
                for (int g = 0; g < 4; ++g)
                    #pragma unroll
                    for (int kk = 0; kk < 16; ++kk)
                        v[g * 8 + bb] += u[g][kk] * hh[kk];
            }

            // reduce-scatter over 32 kc lanes
            float a16[16];
            #pragma unroll
            for (int i = 0; i < 16; ++i) {
                float keep = (kc & 16) ? v[i + 16] : v[i];
                float give = (kc & 16) ? v[i]      : v[i + 16];
                a16[i] = keep + __shfl_xor(give, 16, 32);
            }
            float a8[8];
            #pragma unroll
            for (int i = 0; i < 8; ++i) {
                float keep = (kc & 8) ? a16[i + 8] : a16[i];
                float give = (kc & 8) ? a16[i]     : a16[i + 8];
                a8[i] = keep + __shfl_xor(give, 8, 32);
            }
            float a4[4];
            #pragma unroll
            for (int i = 0; i < 4; ++i) {
                float keep = (kc & 4) ? a8[i + 4] : a8[i];
                float give = (kc & 4) ? a8[i]     : a8[i + 4];
                a4[i] = keep + __shfl_xor(give, 4, 32);
            }
            float a2[2];
            #pragma unroll
            for (int i = 0; i < 2; ++i) {
                float keep = (kc & 2) ? a4[i + 2] : a4[i];
                float give = (kc & 2) ? a4[i]     : a4[i + 2];
                a2[i] = keep + __shfl_xor(give, 2, 32);
            }
            float keep1 = (kc & 1) ? a2[1] : a2[0];
            float give1 = (kc & 1) ? a2[0] : a2[1];
            float z = keep1 + __shfl_xor(give1, 1, 32) + zpre;
            zpre = zpre_next;

            float z8  = __shfl_xor(z, 8, 32);
            float z16 = __shfl_xor(z, 16, 32);
            float z24 = __shfl_xor(z, 24, 32);
            float i_ = fsigm(z);
            float f_ = fsigm(z8);
            float gg = ftanh(z16);
            float o_ = fsigm(z24);
            c_reg = f_ * c_reg + i_ * gg;
            float h_ = o_ * ftanh(c_reg);

            if (g_ == 0)
                store_coherent(&H0x[(size_t)(t + 1) * (B_ * HID_)
                                    + (b0 + bb_) * HID_ + j0 + jj], h_);

            DRAIN_STORES();                        // asm stores at IF$ before arrival
            __syncthreads();                       // SYNC_C
            if (tid == 0) {
                unsigned old = AADD(shard0);
                if (old + 1u == 16u * (unsigned)(t + 1)) AADD(root0);
            }
        }
    } else {
        // ---------------- LAYER 1 ----------------
        // concatenated K=1024: kc<16 -> W1 rows (x part), kc>=16 -> U1 (h part)
        float u[4][32];
        #pragma unroll
        for (int g = 0; g < 4; ++g)
            #pragma unroll
            for (int kk = 0; kk < 32; ++kk) {
                const int K = kc * 32 + kk;
                u[g][kk] = (K < 512)
                    ? W1[(size_t)K * G4_ + (g << 9) + j0 + jj]
                    : U1[(size_t)(K - 512) * G4_ + (g << 9) + j0 + jj];
            }
        const float zb = b1[(g_ << 9) + j0 + jj];
        float c_reg = 0.f;

        for (int t = 0; t < T_; ++t) {
            if (tid == 0) {
                wait_ge(root0, 4u * (unsigned)(t + 1));          // h0(t) ready
                if (t > 0) wait_ge(root1, 4u * (unsigned)t);     // h1(t) ready
            }
            __syncthreads();                       // SYNC_A

            // stage [x=h0(t) | h1(t)] [8][1024] -> lds[b][kc][36]
            {
                const float* xbase = H0x  + (size_t)(t + 1) * (B_ * HID_);
                const float* hbase = h1buf + (size_t)(t & 1) * (B_ * HID_);
                const float* p[8]; float* dst[8];
                const int k = tid * 4;             // 0..1020
                #pragma unroll
                for (int q = 0; q < 8; ++q) {
                    p[q] = (k < 512) ? (xbase + (b0 + q) * HID_ + k)
                                     : (hbase + (b0 + q) * HID_ + (k - 512));
                    dst[q] = &lds[q * 1152 + (tid >> 3) * 36 + (tid & 7) * 4];
                }
                f32x4 v0, v1, v2, v3, v4, v5, v6, v7;
                load4_coherent(p[0], p[1], p[2], p[3], v0, v1, v2, v3);
                load4_coherent(p[4], p[5], p[6], p[7], v4, v5, v6, v7);
                *(f32x4*)dst[0] = v0; *(f32x4*)dst[1] = v1;
                *(f32x4*)dst[2] = v2; *(f32x4*)dst[3] = v3;
                *(f32x4*)dst[4] = v4; *(f32x4*)dst[5] = v5;
                *(f32x4*)dst[6] = v6; *(f32x4*)dst[7] = v7;
            }
            __syncthreads();                       // SYNC_B

            float v[32];
            #pragma unroll
            for (int s = 0; s < 32; ++s) v[s] = 0.f;
            #pragma unroll
            for (int bb = 0; bb < 8; ++bb) {
                const float* hp = &lds[bb * 1152 + kc * 36];
                #pragma unroll
                for (int half = 0; half < 2; ++half) {
                    f32x4 h0v = *(const f32x4*)(hp + half * 16 + 0);
                    f32x4 h1v = *(const f32x4*)(hp + half * 16 + 4);
                    f32x4 h2v = *(const f32x4*)(hp + half * 16 + 8);
                    f32x4 h3v = *(const f32x4*)(hp + half * 16 + 12);
                    const float hh[16] = {h0v.x, h0v.y, h0v.z, h0v.w, h1v.x, h1v.y, h1v.z, h1v.w,
                                          h2v.x, h2v.y, h2v.z, h2v.w, h3v.x, h3v.y, h3v.z, h3v.w};
                    #pragma unroll
                    for (int g = 0; g < 4; ++g)
                        #pragma unroll
                        for (int kk = 0; kk < 16; ++kk)
                            v[g * 8 + bb] += u[g][half * 16 + kk] * hh[kk];
                }
            }

            float a16[16];
            #pragma unroll
            for (int i = 0; i < 16; ++i) {
                float keep = (kc & 16) ? v[i + 16] : v[i];
                float give = (kc & 16) ? v[i]      : v[i + 16];
                a16[i] = keep + __shfl_xor(give, 16, 32);
            }
            float a8[8];
            #pragma unroll
            for (int i = 0; i < 8; ++i) {
                float keep = (kc & 8) ? a16[i + 8] : a16[i];
                float give = (kc & 8) ? a16[i]     : a16[i + 8];
                a8[i] = keep + __shfl_xor(give, 8, 32);
            }
            float a4[4];
            #pragma unroll
            for (int i = 0; i < 4; ++i) {
                float keep = (kc & 4) ? a8[i + 4] : a8[i];
                float give = (kc & 4) ? a8[i]     : a8[i + 4];
                a4[i] = keep + __shfl_xor(give, 4, 32);
            }
            float a2[2];
            #pragma unroll
            for (int i = 0; i < 2; ++i) {
                float keep = (kc & 2) ? a4[i + 2] : a4[i];
                float give = (kc & 2) ? a4[i]     : a4[i + 2];
                a2[i] = keep + __shfl_xor(give, 2, 32);
            }
            float keep1 = (kc & 1) ? a2[1] : a2[0];
            float give1 = (kc & 1) ? a2[0] : a2[1];
            float z = keep1 + __shfl_xor(give1, 1, 32) + zb;

            float z8  = __shfl_xor(z, 8, 32);
            float z16 = __shfl_xor(z, 16, 32);
            float z24 = __shfl_xor(z, 24, 32);
            float i_ = fsigm(z);
            float f_ = fsigm(z8);
            float gg = ftanh(z16);
            float o_ = fsigm(z24);
            c_reg = f_ * c_reg + i_ * gg;
            float h_ = o_ * ftanh(c_reg);

            if (g_ == 0) {
                const int brow = b0 + bb_;
                store_coherent(&h1buf[(size_t)((t + 1) & 1) * (B_ * HID_)
                                      + brow * HID_ + j0 + jj], h_);
                u16 hi, lo; bsplit(h_, hi, lo);
                const size_t o = ((size_t)t * B_ + brow) * HID_ + j0 + jj;
                Ahi[o] = hi;
                Alo[o] = lo;
            }

            DRAIN_STORES();                        // asm stores at IF$ before arrival
            __syncthreads();                       // SYNC_C
            if (tid == 0) {
                unsigned old = AADD(shard1);
                if (old + 1u == 16u * (unsigned)(t + 1)) AADD(root1);
            }
        }
    }
}

// ---------------------------------------------------------------------------
extern "C" void kernel_launch(void* const* d_in, const int* in_sizes, int n_in,
                              void* d_out, int out_size, void* d_ws, size_t ws_size,
                              hipStream_t stream)
{
    const int*   tokens = (const int*)  d_in[0];
    const float* emb    = (const float*)d_in[1];
    const float* W0     = (const float*)d_in[2];
    const float* U0     = (const float*)d_in[3];
    const float* b0     = (const float*)d_in[4];
    const float* W1     = (const float*)d_in[5];
    const float* U1     = (const float*)d_in[6];
    const float* b1     = (const float*)d_in[7];
    const float* Wout   = (const float*)d_in[8];
    const float* bout   = (const float*)d_in[9];
    float* out = (float*)d_out;

    // d_out scratch: G (8192x2048 fp32 swizzled) then H0x ([T+1][32][512]) --
    // both dead before the final GEMM overwrites all of d_out.
    float* G   = out;
    float* H0x = out + (size_t)8192 * 2048;

    u16* ws16 = (u16*)d_ws;
    size_t o = 0;
    u16* Ahi   = ws16 + o; o += (size_t)8192 * 512;
    u16* Alo   = ws16 + o; o += (size_t)8192 * 512;
    u16* W0Thi = ws16 + o; o += (size_t)G4_ * 512;
    u16* W0Tlo = ws16 + o; o += (size_t)G4_ * 512;
    u16* WoThi = ws16 + o; o += (size_t)NPAD_ * 512;
    u16* WoTlo = ws16 + o; o += (size_t)NPAD_ * 512;
    float*    h1buf = (float*)(ws16 + o);
    unsigned* bar   = (unsigned*)(h1buf + 2 * B_ * HID_);

    dim3 blk(256);

    // prep: weight transpose+split (W0, Wout) and embedding gather+split
    wsplit_k<<<dim3(G4_ / 64, 8), blk, 0, stream>>>(W0, W0Thi, W0Tlo, G4_);
    wsplit_k<<<dim3(NPAD_ / 64, 8), blk, 0, stream>>>(Wout, WoThi, WoTlo, VOC_);
    gather_split_k<<<dim3(2048), blk, 0, stream>>>(tokens, emb, Ahi, Alo);

    // G = X0 @ W0 + b0   (split-bf16 MFMA, recurrence-swizzled store)
    gemm_bf16_k<0><<<dim3(G4_ / 128, 64), blk, 0, stream>>>(
        Ahi, Alo, W0Thi, W0Tlo, b0, G, G4_);

    // fused 2-layer recurrence -> Ahi/Alo (h1 bf16)
    hipMemsetAsync(H0x, 0, B_ * HID_ * sizeof(float), stream);    // h0(0) = 0
    hipMemsetAsync(h1buf, 0, B_ * HID_ * sizeof(float), stream);  // h1(0) = 0
    hipMemsetAsync(bar, 0, 1024 * sizeof(unsigned), stream);      // barriers
    fused_rec_k<<<dim3(512), blk, 0, stream>>>(
        G, U0, W1, U1, b1, H0x, Ahi, Alo, h1buf, bar);

    // out[b*T+t, :] = H1 @ W_out + b_out
    gemm_bf16_k<1><<<dim3(NPAD_ / 128, 64), blk, 0, stream>>>(
        Ahi, Alo, WoThi, WoTlo, bout, out, NPAD_);
}